// Round 1
// 974.969 us; speedup vs baseline: 1.0022x; 1.0022x over previous
//
#include <hip/hip_runtime.h>
#include <math.h>

#define B_ 32
#define N_ 2048
#define ROWS_PER_WAVE 4
#define WAVES_PER_BLOCK 4
#define ROWS_PER_BLOCK (ROWS_PER_WAVE * WAVES_PER_BLOCK)   // 16
#define BLOCKS_PER_BATCH (N_ / ROWS_PER_BLOCK)             // 128

// Single fused kernel: complex batched matvec + full epilogue.
// - x_r/x_i held in registers per wave (no LDS, no barrier)
// - per-batch scale computed redundantly per wave from the register copy
// - 4 rows per wave with cross-row interleaved loads for memory-level parallelism
// - complex parts combined into (sr, si) BEFORE the cross-lane reduce (12 shuffles/row, not 24)
__global__ __launch_bounds__(256) void fused_sync_kernel(
    const float* __restrict__ Yr, const float* __restrict__ Yi,
    const float* __restrict__ x_r, const float* __restrict__ x_i,
    const float* __restrict__ xp_r, const float* __restrict__ xp_i,
    const float* __restrict__ d3w, const float* __restrict__ d3b,
    const float* __restrict__ w1, const float* __restrict__ b1,
    const float* __restrict__ w2, const float* __restrict__ b2,
    float* __restrict__ out)
{
    const int t    = threadIdx.x;
    const int lane = t & 63;
    const int wave = t >> 6;
    const int b    = blockIdx.x / BLOCKS_PER_BATCH;
    const int row0 = (blockIdx.x % BLOCKS_PER_BATCH) * ROWS_PER_BLOCK
                   + wave * ROWS_PER_WAVE;

    // ---- x for this batch into registers: lane holds elements lane+64*it (x4) ----
    const float4* gxr = (const float4*)(x_r + (size_t)b * N_);
    const float4* gxi = (const float4*)(x_i + (size_t)b * N_);
    float4 xr[8], xi[8];
    #pragma unroll
    for (int it = 0; it < 8; ++it) {
        xr[it] = gxr[lane + it * 64];
        xi[it] = gxi[lane + it * 64];
    }

    // ---- MLP weights: 4 hidden units per lane (lane, +64, +128, +192) ----
    float w1v[4], b1v[4], w2v[4];
    #pragma unroll
    for (int k = 0; k < 4; ++k) {
        w1v[k] = w1[lane + 64 * k];
        b1v[k] = b1[lane + 64 * k];
        w2v[k] = w2[lane + 64 * k];
    }
    const float d3w_v = d3w[0], d3b_v = d3b[0], b2v = b2[0];

    // ---- per-batch scale = -(L^2)*(1 - mean|x|^2), computed from register copy ----
    float ss = 0.f;
    #pragma unroll
    for (int it = 0; it < 8; ++it) {
        ss += xr[it].x * xr[it].x + xr[it].y * xr[it].y
            + xr[it].z * xr[it].z + xr[it].w * xr[it].w;
        ss += xi[it].x * xi[it].x + xi[it].y * xi[it].y
            + xi[it].z * xi[it].z + xi[it].w * xi[it].w;
    }
    #pragma unroll
    for (int m = 1; m < 64; m <<= 1) ss += __shfl_xor(ss, m, 64);
    const float sc = -2.25f * (1.0f - ss * (1.0f / (float)N_));   // L=1.5

    // ---- main loop: 4 rows, loads interleaved across rows per column step ----
    const size_t ybase = ((size_t)b * N_ + row0) * (size_t)N_;
    float sr[4] = {0.f, 0.f, 0.f, 0.f};
    float si[4] = {0.f, 0.f, 0.f, 0.f};

    #pragma unroll
    for (int it = 0; it < 8; ++it) {
        const int idx = lane + it * 64;
        float4 a[4], c[4];
        #pragma unroll
        for (int r = 0; r < 4; ++r) {
            a[r] = *(const float4*)(Yr + ybase + (size_t)r * N_ + 4 * (size_t)idx);
            c[r] = *(const float4*)(Yi + ybase + (size_t)r * N_ + 4 * (size_t)idx);
        }
        const float4 u = xr[it];
        const float4 v = xi[it];
        #pragma unroll
        for (int r = 0; r < 4; ++r) {
            sr[r] += a[r].x * u.x + a[r].y * u.y + a[r].z * u.z + a[r].w * u.w
                   - (c[r].x * v.x + c[r].y * v.y + c[r].z * v.z + c[r].w * v.w);
            si[r] += a[r].x * v.x + a[r].y * v.y + a[r].z * v.z + a[r].w * v.w
                   + c[r].x * u.x + c[r].y * u.y + c[r].z * u.z + c[r].w * u.w;
        }
    }

    // ---- cross-lane butterfly: 8 independent chains (4 rows x {sr, si}) ----
    #pragma unroll
    for (int m = 1; m < 64; m <<= 1) {
        #pragma unroll
        for (int r = 0; r < 4; ++r) {
            sr[r] += __shfl_xor(sr[r], m, 64);
            si[r] += __shfl_xor(si[r], m, 64);
        }
    }

    // ---- epilogue for 4 rows (interleaved; all lanes hold full sums) ----
    float x1r[4], x1i[4], xabs[4], p[4];
    #pragma unroll
    for (int r = 0; r < 4; ++r) {
        float vr = 1.5f * sr[r];
        float vi = 1.5f * si[r];
        vr = vr * d3w_v + d3b_v;                 // Dense(1)
        vi = vi * d3w_v + d3b_v;
        vr += sc * xp_r[(size_t)b * N_ + row0 + r];
        vi += sc * xp_i[(size_t)b * N_ + row0 + r];
        x1r[r] = vr;
        x1i[r] = vi;
        xabs[r] = sqrtf(vr * vr + vi * vi);
        float pp = 0.f;
        #pragma unroll
        for (int k = 0; k < 4; ++k) {
            float h = fmaxf(xabs[r] * w1v[k] + b1v[k], 0.f);
            pp += h * w2v[k];
        }
        p[r] = pp;
    }
    #pragma unroll
    for (int m = 1; m < 64; m <<= 1) {
        #pragma unroll
        for (int r = 0; r < 4; ++r) p[r] += __shfl_xor(p[r], m, 64);
    }

    if (lane == 0) {
        #pragma unroll
        for (int r = 0; r < 4; ++r) {
            const float g = tanhf(p[r] + b2v);
            const float q = g / fmaxf(xabs[r], 1e-12f);
            out[(size_t)b * N_ + row0 + r]                    = x1r[r] * q;
            out[(size_t)B_ * N_ + (size_t)b * N_ + row0 + r]  = x1i[r] * q;
        }
    }
}

extern "C" void kernel_launch(void* const* d_in, const int* in_sizes, int n_in,
                              void* d_out, int out_size, void* d_ws, size_t ws_size,
                              hipStream_t stream) {
    const float* Yr   = (const float*)d_in[0];
    const float* Yi   = (const float*)d_in[1];
    const float* x_r  = (const float*)d_in[2];
    const float* x_i  = (const float*)d_in[3];
    const float* xp_r = (const float*)d_in[4];
    const float* xp_i = (const float*)d_in[5];
    const float* d3w  = (const float*)d_in[6];
    const float* d3b  = (const float*)d_in[7];
    const float* w1   = (const float*)d_in[8];
    const float* b1   = (const float*)d_in[9];
    const float* w2   = (const float*)d_in[10];
    const float* b2   = (const float*)d_in[11];
    float* out = (float*)d_out;

    fused_sync_kernel<<<(B_ * N_) / ROWS_PER_BLOCK, 256, 0, stream>>>(
        Yr, Yi, x_r, x_i, xp_r, xp_i, d3w, d3b, w1, b1, w2, b2, out);
}